// Round 4
// baseline (497.685 us; speedup 1.0000x reference)
//
#include <hip/hip_runtime.h>
#include <math.h>

#define B_ 8
#define N_ 1024
#define C_ 768
#define H_ 8
#define D_ 96
#define SCALE_F 0.1020620726159657f /* 96^-0.5 */

typedef unsigned short u16;
typedef __bf16 bf16x8 __attribute__((ext_vector_type(8)));
typedef float f32x4 __attribute__((ext_vector_type(4)));

#define MFMA(a, b, c) __builtin_amdgcn_mfma_f32_16x16x32_bf16(a, b, c, 0, 0, 0)

__device__ inline void split1(float x, u16& h, u16& l) {
    __bf16 hb = (__bf16)x;
    float hf = (float)hb;
    __bf16 lb = (__bf16)(x - hf);
    h = __builtin_bit_cast(u16, hb);
    l = __builtin_bit_cast(u16, lb);
}

__device__ inline void split1b(float x, __bf16& h, __bf16& l) {
    h = (__bf16)x;
    l = (__bf16)(x - (float)h);
}

__device__ inline void split4(float4 x, ushort4& h, ushort4& l) {
    split1(x.x, h.x, l.x);
    split1(x.y, h.y, l.y);
    split1(x.z, h.z, l.z);
    split1(x.w, h.w, l.w);
}

// ---------------------------------------------------------------------------
// Kernel 1: conv3x3 (SAME) on 8192 images of 3x16x16 -> q, k, v f32 (B,H,N,D)
// ---------------------------------------------------------------------------
__global__ __launch_bounds__(256) void conv_qkv(
    const float* __restrict__ x,
    const float* __restrict__ qw, const float* __restrict__ qb,
    const float* __restrict__ kw, const float* __restrict__ kb,
    const float* __restrict__ vw, const float* __restrict__ vb,
    float* __restrict__ q, float* __restrict__ k, float* __restrict__ v)
{
    __shared__ float simg[768];
    __shared__ float sw[243];
    __shared__ float sb[9];
    const int img = blockIdx.x;
    const int b = img >> 10;
    const int tid = threadIdx.x;

    for (int i = tid; i < 768; i += 256) simg[i] = x[(size_t)img * 768 + i];
    if (tid < 243) {
        int g = tid / 81, i = tid % 81;
        const float* w = (g == 0) ? qw : (g == 1) ? kw : vw;
        sw[tid] = w[i];
    }
    if (tid < 9) {
        int g = tid / 3, i = tid % 3;
        const float* bb = (g == 0) ? qb : (g == 1) ? kb : vb;
        sb[tid] = bb[i];
    }
    __syncthreads();

    const int n = img & 1023;
    for (int e = tid; e < 2304; e += 256) {
        int g = e / 768, c = e % 768;
        int oc = c >> 8, rem = c & 255, y = rem >> 4, xx = rem & 15;
        float acc = sb[g * 3 + oc];
        const float* wg = &sw[g * 81 + oc * 27];
        #pragma unroll
        for (int ic = 0; ic < 3; ++ic)
            #pragma unroll
            for (int ky = 0; ky < 3; ++ky) {
                int yy = y + ky - 1;
                if (yy < 0 || yy > 15) continue;
                #pragma unroll
                for (int kx = 0; kx < 3; ++kx) {
                    int xp = xx + kx - 1;
                    if (xp < 0 || xp > 15) continue;
                    acc += wg[ic * 9 + ky * 3 + kx] * simg[ic * 256 + yy * 16 + xp];
                }
            }
        int h = c / 96, d = c % 96;
        float* dst = (g == 0) ? q : (g == 1) ? k : v;
        dst[((size_t)(b * 8 + h) * 1024 + n) * 96 + d] = acc;
    }
}

// ---------------------------------------------------------------------------
// Kernel 2: split q,k f32 -> bf16 hi/lo, row-major (bh, n, 96)
// ---------------------------------------------------------------------------
__global__ __launch_bounds__(256) void qk_split(
    const float* __restrict__ q, const float* __restrict__ k,
    u16* __restrict__ qh, u16* __restrict__ ql,
    u16* __restrict__ kh, u16* __restrict__ kl)
{
    size_t i = (size_t)(blockIdx.x * 256 + threadIdx.x) * 4;
    const float* src = blockIdx.y ? k : q;
    u16* dh = blockIdx.y ? kh : qh;
    u16* dl = blockIdx.y ? kl : ql;
    float4 x = *(const float4*)&src[i];
    ushort4 h, l;
    split4(x, h, l);
    *(ushort4*)&dh[i] = h;
    *(ushort4*)&dl[i] = l;
}

// ---------------------------------------------------------------------------
// Kernel 3: transpose+split V: (b,h,n,d) f32 -> vt_h/vt_l (b,h,d,n) bf16
// ---------------------------------------------------------------------------
__global__ __launch_bounds__(256) void vt_split(
    const float* __restrict__ v, u16* __restrict__ vt_h, u16* __restrict__ vt_l)
{
    __shared__ float t32[32][36];
    const int bh = blockIdx.z, n0 = blockIdx.x * 32, d0 = blockIdx.y * 32;
    const int tid = threadIdx.x;
    {
        int nn = tid >> 3, c4 = (tid & 7) * 4;
        float4 x = *(const float4*)&v[((size_t)bh * 1024 + n0 + nn) * 96 + d0 + c4];
        t32[nn][c4] = x.x; t32[nn][c4 + 1] = x.y;
        t32[nn][c4 + 2] = x.z; t32[nn][c4 + 3] = x.w;
    }
    __syncthreads();
    {
        int d = tid >> 3, n4 = (tid & 7) * 4;
        float4 y = make_float4(t32[n4][d], t32[n4 + 1][d], t32[n4 + 2][d], t32[n4 + 3][d]);
        ushort4 h, l;
        split4(y, h, l);
        size_t o = ((size_t)bh * 96 + d0 + d) * 1024 + n0 + n4;
        *(ushort4*)&vt_h[o] = h;
        *(ushort4*)&vt_l[o] = l;
    }
}

// ---------------------------------------------------------------------------
// Kernel 4: split pw f32 -> pw_h/pw_l bf16
// ---------------------------------------------------------------------------
__global__ __launch_bounds__(256) void pw_split(
    const float* __restrict__ pw, u16* __restrict__ pwh, u16* __restrict__ pwl)
{
    int i = blockIdx.x * 256 + threadIdx.x;
    float4 x = *(const float4*)&pw[(size_t)i * 4];
    ushort4 h, l;
    split4(x, h, l);
    *(ushort4*)&pwh[(size_t)i * 4] = h;
    *(ushort4*)&pwl[(size_t)i * 4] = l;
}

// ---------------------------------------------------------------------------
// Kernel 5: QK stats pass: per (b,h,row) compute max and 1/sum of
// exp(SCALE*q.k - max) via online softmax. MFMA sequence identical to the
// fused pass -> bit-identical s -> exact normalization.
// grid (8 nblk, 64 bh), 256 thr (4 waves x 32 rows).
// ---------------------------------------------------------------------------
__global__ __launch_bounds__(256) void qk_stats(
    const u16* __restrict__ qh, const u16* __restrict__ ql,
    const u16* __restrict__ kh, const u16* __restrict__ kl,
    float* __restrict__ smx, float* __restrict__ srv)
{
    const int bh = blockIdx.y;
    const int n0 = blockIdx.x * 128;
    const int tid = threadIdx.x, wid = tid >> 6, lane = tid & 63;
    const int l16 = lane & 15, kg = lane >> 4;
    const int nbase = n0 + wid * 32;

    bf16x8 qhf[2][3], qlf[2][3];
    #pragma unroll
    for (int nf = 0; nf < 2; ++nf)
        #pragma unroll
        for (int ks = 0; ks < 3; ++ks) {
            size_t off = ((size_t)bh * 1024 + nbase + nf * 16 + l16) * 96 + ks * 32 + kg * 8;
            qhf[nf][ks] = *(const bf16x8*)&qh[off];
            qlf[nf][ks] = *(const bf16x8*)&ql[off];
        }

    float mx[2][4], ls[2][4];
    #pragma unroll
    for (int nf = 0; nf < 2; ++nf)
        #pragma unroll
        for (int r = 0; r < 4; ++r) { mx[nf][r] = -INFINITY; ls[nf][r] = 0.f; }

    for (int mt = 0; mt < 16; ++mt) {
        const int m0 = mt * 64;
        f32x4 sacc[2][4];
        #pragma unroll
        for (int nf = 0; nf < 2; ++nf)
            #pragma unroll
            for (int mf = 0; mf < 4; ++mf) sacc[nf][mf] = (f32x4){0.f, 0.f, 0.f, 0.f};

        #pragma unroll
        for (int ks = 0; ks < 3; ++ks) {
            bf16x8 kbh[4], kbl[4];
            #pragma unroll
            for (int mf = 0; mf < 4; ++mf) {
                size_t off = ((size_t)bh * 1024 + m0 + mf * 16 + l16) * 96 + ks * 32 + kg * 8;
                kbh[mf] = *(const bf16x8*)&kh[off];
                kbl[mf] = *(const bf16x8*)&kl[off];
            }
            #pragma unroll
            for (int nf = 0; nf < 2; ++nf)
                #pragma unroll
                for (int mf = 0; mf < 4; ++mf) {
                    sacc[nf][mf] = MFMA(qhf[nf][ks], kbh[mf], sacc[nf][mf]);
                    sacc[nf][mf] = MFMA(qhf[nf][ks], kbl[mf], sacc[nf][mf]);
                    sacc[nf][mf] = MFMA(qlf[nf][ks], kbh[mf], sacc[nf][mf]);
                }
        }

        #pragma unroll
        for (int nf = 0; nf < 2; ++nf)
            #pragma unroll
            for (int r = 0; r < 4; ++r) {
                float s0 = sacc[nf][0][r] * SCALE_F;
                float s1 = sacc[nf][1][r] * SCALE_F;
                float s2 = sacc[nf][2][r] * SCALE_F;
                float s3 = sacc[nf][3][r] * SCALE_F;
                float v = fmaxf(fmaxf(s0, s1), fmaxf(s2, s3));
                #pragma unroll
                for (int off = 1; off < 16; off <<= 1) v = fmaxf(v, __shfl_xor(v, off));
                float mnew = fmaxf(mx[nf][r], v);
                float ssum = __expf(s0 - mnew) + __expf(s1 - mnew) +
                             __expf(s2 - mnew) + __expf(s3 - mnew);
                #pragma unroll
                for (int off = 1; off < 16; off <<= 1) ssum += __shfl_xor(ssum, off);
                ls[nf][r] = ls[nf][r] * __expf(mx[nf][r] - mnew) + ssum;
                mx[nf][r] = mnew;
            }
    }

    if (l16 == 0) {
        #pragma unroll
        for (int nf = 0; nf < 2; ++nf)
            #pragma unroll
            for (int r = 0; r < 4; ++r) {
                int row = nbase + nf * 16 + kg * 4 + r;
                smx[(size_t)bh * 1024 + row] = mx[nf][r];
                srv[(size_t)bh * 1024 + row] = 1.0f / ls[nf][r];
            }
    }
}

// ---------------------------------------------------------------------------
// Kernel 6: fused QK + softmax + head-mix + BN + attn-write + PV.
// grid (32 nblk, 8 b), 512 thr (8 waves). Wave w = head w (QK) = out-head w
// (mix+PV). ntile=32 rows, m-tile=32.
// ---------------------------------------------------------------------------
__global__ __launch_bounds__(512) void fused_attn(
    const u16* __restrict__ qh, const u16* __restrict__ ql,
    const u16* __restrict__ kh, const u16* __restrict__ kl,
    const u16* __restrict__ vth, const u16* __restrict__ vtl,
    const float* __restrict__ smx, const float* __restrict__ srv,
    const float* __restrict__ rw, const float* __restrict__ rb,
    const float* __restrict__ bn_g, const float* __restrict__ bn_b,
    const float* __restrict__ bn_m, const float* __restrict__ bn_v,
    float* __restrict__ attn, u16* __restrict__ o1h, u16* __restrict__ o1l)
{
    __shared__ float p_lds[8][32][36];
    __shared__ float m_lds[8][32][36];
    __shared__ float s_mx[8][32], s_rv[8][32];
    __shared__ float s_w2[8][8];
    __shared__ float s_b2[8];

    const int b = blockIdx.y, n0 = blockIdx.x * 32;
    const int tid = threadIdx.x, wid = tid >> 6, lane = tid & 63;
    const int l16 = lane & 15, kg = lane >> 4;
    const int h = wid;
    const size_t bh = (size_t)b * 8 + h;

    if (tid < 64) {
        int o = tid >> 3, hh = tid & 7;
        float inv = bn_g[o] * rsqrtf(bn_v[o] + 1e-5f);
        s_w2[o][hh] = rw[o * 8 + hh] * inv;
        if (hh == 0) s_b2[o] = (rb[o] - bn_m[o]) * inv + bn_b[o];
    }
    if (tid < 256) {
        int hh = tid >> 5, n = tid & 31;
        s_mx[hh][n] = smx[(size_t)(b * 8 + hh) * 1024 + n0 + n];
        s_rv[hh][n] = srv[(size_t)(b * 8 + hh) * 1024 + n0 + n];
    }

    // resident Q fragments (this wave's head, 32 rows)
    bf16x8 qhf[2][3], qlf[2][3];
    #pragma unroll
    for (int nf = 0; nf < 2; ++nf)
        #pragma unroll
        for (int ks = 0; ks < 3; ++ks) {
            size_t off = (bh * 1024 + n0 + nf * 16 + l16) * 96 + ks * 32 + kg * 8;
            qhf[nf][ks] = *(const bf16x8*)&qh[off];
            qlf[nf][ks] = *(const bf16x8*)&ql[off];
        }

    f32x4 pvacc[2][6];
    #pragma unroll
    for (int nf = 0; nf < 2; ++nf)
        #pragma unroll
        for (int df = 0; df < 6; ++df) pvacc[nf][df] = (f32x4){0.f, 0.f, 0.f, 0.f};

    __syncthreads();

    for (int mt = 0; mt < 32; ++mt) {
        const int m0 = mt * 32;

        // ---- QK for my head: s[32n x 32m] ----
        f32x4 sacc[2][2];
        #pragma unroll
        for (int nf = 0; nf < 2; ++nf)
            #pragma unroll
            for (int mf = 0; mf < 2; ++mf) sacc[nf][mf] = (f32x4){0.f, 0.f, 0.f, 0.f};
        #pragma unroll
        for (int ks = 0; ks < 3; ++ks) {
            bf16x8 kbh[2], kbl[2];
            #pragma unroll
            for (int mf = 0; mf < 2; ++mf) {
                size_t off = (bh * 1024 + m0 + mf * 16 + l16) * 96 + ks * 32 + kg * 8;
                kbh[mf] = *(const bf16x8*)&kh[off];
                kbl[mf] = *(const bf16x8*)&kl[off];
            }
            #pragma unroll
            for (int nf = 0; nf < 2; ++nf)
                #pragma unroll
                for (int mf = 0; mf < 2; ++mf) {
                    sacc[nf][mf] = MFMA(qhf[nf][ks], kbh[mf], sacc[nf][mf]);
                    sacc[nf][mf] = MFMA(qhf[nf][ks], kbl[mf], sacc[nf][mf]);
                    sacc[nf][mf] = MFMA(qlf[nf][ks], kbh[mf], sacc[nf][mf]);
                }
        }

        // ---- p = exp(s*SCALE - mx) * rinv -> p_lds ----
        #pragma unroll
        for (int nf = 0; nf < 2; ++nf)
            #pragma unroll
            for (int mf = 0; mf < 2; ++mf)
                #pragma unroll
                for (int r = 0; r < 4; ++r) {
                    int n = nf * 16 + kg * 4 + r;
                    float pp = __expf(sacc[nf][mf][r] * SCALE_F - s_mx[h][n]) * s_rv[h][n];
                    p_lds[h][n][mf * 16 + l16] = pp;
                }
        __syncthreads();

        // ---- mix for out-head o = wid (A-fragment layout: n=l16, m=kg*8+j)
        float mixf[2][8];
        #pragma unroll
        for (int nf = 0; nf < 2; ++nf)
            #pragma unroll
            for (int j = 0; j < 8; ++j) mixf[nf][j] = s_b2[h];
        #pragma unroll
        for (int hh = 0; hh < 8; ++hh) {
            float w = s_w2[h][hh];
            #pragma unroll
            for (int nf = 0; nf < 2; ++nf) {
                float4 a0 = *(const float4*)&p_lds[hh][nf * 16 + l16][kg * 8];
                float4 a1 = *(const float4*)&p_lds[hh][nf * 16 + l16][kg * 8 + 4];
                mixf[nf][0] += w * a0.x; mixf[nf][1] += w * a0.y;
                mixf[nf][2] += w * a0.z; mixf[nf][3] += w * a0.w;
                mixf[nf][4] += w * a1.x; mixf[nf][5] += w * a1.y;
                mixf[nf][6] += w * a1.z; mixf[nf][7] += w * a1.w;
            }
        }
        // write mixed to LDS (for coalesced global write) + split to A-frags
        bf16x8 mah[2], mal[2];
        #pragma unroll
        for (int nf = 0; nf < 2; ++nf) {
            *(float4*)&m_lds[h][nf * 16 + l16][kg * 8] =
                make_float4(mixf[nf][0], mixf[nf][1], mixf[nf][2], mixf[nf][3]);
            *(float4*)&m_lds[h][nf * 16 + l16][kg * 8 + 4] =
                make_float4(mixf[nf][4], mixf[nf][5], mixf[nf][6], mixf[nf][7]);
            #pragma unroll
            for (int j = 0; j < 8; ++j) {
                __bf16 hb, lb;
                split1b(mixf[nf][j], hb, lb);
                mah[nf][j] = hb;
                mal[nf][j] = lb;
            }
        }
        __syncthreads();

        // ---- coalesced global write of mixed attn (8o x 32n x 32m) ----
        {
            int row = tid >> 1, half = tid & 1;
            int o = row >> 5, n = row & 31;
            float* gp = &attn[((size_t)(b * 8 + o) * 1024 + n0 + n) * 1024 + m0 + half * 16];
            const float* sp = &m_lds[o][n][half * 16];
            #pragma unroll
            for (int j = 0; j < 4; ++j)
                *(float4*)&gp[j * 4] = *(const float4*)&sp[j * 4];
        }

        // ---- PV accumulate for o = wid: out1 += mixed[32n x 32m] * V[32m x 96d]
        #pragma unroll
        for (int df = 0; df < 6; ++df) {
            size_t off = (bh * 96 + df * 16 + l16) * 1024 + m0 + kg * 8;
            bf16x8 vbh = *(const bf16x8*)&vth[off];
            bf16x8 vbl = *(const bf16x8*)&vtl[off];
            #pragma unroll
            for (int nf = 0; nf < 2; ++nf) {
                pvacc[nf][df] = MFMA(mah[nf], vbh, pvacc[nf][df]);
                pvacc[nf][df] = MFMA(mah[nf], vbl, pvacc[nf][df]);
                pvacc[nf][df] = MFMA(mal[nf], vbh, pvacc[nf][df]);
            }
        }
        __syncthreads();
    }

    // ---- epilogue: out1 (b, n, h*96+d) split bf16 h/l ----
    #pragma unroll
    for (int nf = 0; nf < 2; ++nf)
        #pragma unroll
        for (int df = 0; df < 6; ++df)
            #pragma unroll
            for (int r = 0; r < 4; ++r) {
                int row = n0 + nf * 16 + kg * 4 + r;
                int col = h * 96 + df * 16 + l16;
                u16 hh, ll;
                split1(pvacc[nf][df][r], hh, ll);
                size_t o = ((size_t)b * 1024 + row) * 768 + col;
                o1h[o] = hh;
                o1l[o] = ll;
            }
}

// ---------------------------------------------------------------------------
// Kernel 7: proj via MFMA. out[t][o] = out1[t][:] . pw[o][:] + pb[o]
// 128t x 64o per block, grid 12x64 = 768 blocks.
// ---------------------------------------------------------------------------
__global__ __launch_bounds__(256) void proj_mfma(
    const u16* __restrict__ o1h, const u16* __restrict__ o1l,
    const u16* __restrict__ pwh, const u16* __restrict__ pwl,
    const float* __restrict__ pb, float* __restrict__ out)
{
    __shared__ __align__(16) u16 Ahs[5120], Als[5120];  // [128][40]
    __shared__ __align__(16) u16 Bhs[2560], Bls[2560];  // [64][40]
    const int t0 = blockIdx.y * 128, o0 = blockIdx.x * 64;
    const int tid = threadIdx.x;
    const int wid = tid >> 6, lane = tid & 63;
    const int l16 = lane & 15, kg = lane >> 4;
    const int wr = wid >> 1, wc = wid & 1;

    f32x4 acc[4][2];
    #pragma unroll
    for (int i = 0; i < 4; ++i)
        #pragma unroll
        for (int j = 0; j < 2; ++j) acc[i][j] = (f32x4){0.f, 0.f, 0.f, 0.f};

    for (int s = 0; s < 24; ++s) {
        const int kc = s * 32;
        if (s) __syncthreads();
        #pragma unroll
        for (int i = 0; i < 4; ++i) {
            int idx = tid + i * 256;
            int r = idx >> 3, c4 = idx & 7;
            *(ushort4*)&Ahs[r * 40 + c4 * 4] = *(const ushort4*)&o1h[(size_t)(t0 + r) * 768 + kc + c4 * 4];
            *(ushort4*)&Als[r * 40 + c4 * 4] = *(const ushort4*)&o1l[(size_t)(t0 + r) * 768 + kc + c4 * 4];
        }
        #pragma unroll
        for (int i = 0; i < 2; ++i) {
            int idx = tid + i * 256;
            int r = idx >> 3, c4 = idx & 7;
            *(ushort4*)&Bhs[r * 40 + c4 * 4] = *(const ushort4*)&pwh[(size_t)(o0 + r) * 768 + kc + c4 * 4];
            *(ushort4*)&Bls[r * 40 + c4 * 4] = *(const ushort4*)&pwl[(size_t)(o0 + r) * 768 + kc + c4 * 4];
        }
        __syncthreads();

        bf16x8 ah[4], al[4], bh8[2], bl8[2];
        #pragma unroll
        for (int f = 0; f < 4; ++f) {
            int ra = (wr * 64 + f * 16 + l16) * 40 + kg * 8;
            ah[f] = *(const bf16x8*)&Ahs[ra];
            al[f] = *(const bf16x8*)&Als[ra];
        }
        #pragma unroll
        for (int j = 0; j < 2; ++j) {
            int rb = (wc * 32 + j * 16 + l16) * 40 + kg * 8;
            bh8[j] = *(const bf16x8*)&Bhs[rb];
            bl8[j] = *(const bf16x8*)&Bls[rb];
        }
        #pragma unroll
        for (int i = 0; i < 4; ++i)
            #pragma unroll
            for (int j = 0; j < 2; ++j) {
                acc[i][j] = MFMA(ah[i], bh8[j], acc[i][j]);
                acc[i][j] = MFMA(ah[i], bl8[j], acc[i][j]);
                acc[i][j] = MFMA(al[i], bh8[j], acc[i][j]);
            }
    }

    #pragma unroll
    for (int i = 0; i < 4; ++i) {
        int rr = t0 + wr * 64 + i * 16 + kg * 4;
        #pragma unroll
        for (int j = 0; j < 2; ++j) {
            int cc = o0 + wc * 32 + j * 16 + l16;
            float bias = pb[cc];
            #pragma unroll
            for (int r = 0; r < 4; ++r)
                out[(size_t)(rr + r) * 768 + cc] = acc[i][j][r] + bias;
        }
    }
}

// ---------------------------------------------------------------------------
extern "C" void kernel_launch(void* const* d_in, const int* in_sizes, int n_in,
                              void* d_out, int out_size, void* d_ws, size_t ws_size,
                              hipStream_t stream)
{
    const float* x    = (const float*)d_in[0];
    const float* qw   = (const float*)d_in[1];
    const float* qb   = (const float*)d_in[2];
    const float* kw   = (const float*)d_in[3];
    const float* kb   = (const float*)d_in[4];
    const float* vw   = (const float*)d_in[5];
    const float* vb   = (const float*)d_in[6];
    const float* rw   = (const float*)d_in[7];
    const float* rb   = (const float*)d_in[8];
    const float* bn_g = (const float*)d_in[9];
    const float* bn_b = (const float*)d_in[10];
    const float* bn_m = (const float*)d_in[11];
    const float* bn_v = (const float*)d_in[12];
    const float* pw   = (const float*)d_in[13];
    const float* pb   = (const float*)d_in[14];

    float* out_p  = (float*)d_out;                  // (B, N, C)
    float* attn_p = out_p + (size_t)B_ * N_ * C_;   // (B, H, N, N)

    float* ws = (float*)d_ws;
    const size_t qkv_sz = (size_t)B_ * H_ * N_ * D_;  // 6,291,456

    float* qbuf = ws;                   // f32 q; later o1h/o1l
    float* kbuf = ws + qkv_sz;          // f32 k
    float* vbuf = ws + 2 * qkv_sz;      // f32 v; later pwh/pwl

    u16* qhp = (u16*)(ws + 3 * qkv_sz);
    u16* qlp = qhp + qkv_sz;
    u16* khp = qlp + qkv_sz;
    u16* klp = khp + qkv_sz;
    u16* vth = (u16*)(ws + 5 * qkv_sz);
    u16* vtl = vth + qkv_sz;
    float* smx = ws + 6 * qkv_sz;       // 65536 f32
    float* srv = smx + 65536;

    u16* o1h = (u16*)qbuf;
    u16* o1l = o1h + qkv_sz;
    u16* pwh = (u16*)vbuf;
    u16* pwl = pwh + (size_t)C_ * C_;

    conv_qkv<<<B_ * N_, 256, 0, stream>>>(x, qw, qb, kw, kb, vw, vb, qbuf, kbuf, vbuf);
    qk_split<<<dim3(6144, 2), 256, 0, stream>>>(qbuf, kbuf, qhp, qlp, khp, klp);
    vt_split<<<dim3(32, 3, 64), 256, 0, stream>>>(vbuf, vth, vtl);
    pw_split<<<576, 256, 0, stream>>>(pw, pwh, pwl);             // v dead -> pw in vbuf
    qk_stats<<<dim3(8, 64), 256, 0, stream>>>(qhp, qlp, khp, klp, smx, srv);
    fused_attn<<<dim3(32, 8), 512, 0, stream>>>(qhp, qlp, khp, klp, vth, vtl,
                                                smx, srv, rw, rb, bn_g, bn_b, bn_m, bn_v,
                                                attn_p, o1h, o1l);                 // q,k dead -> o1 in qbuf
    proj_mfma<<<dim3(12, 64), 256, 0, stream>>>(o1h, o1l, pwh, pwl, pb, out_p);
}

// Round 7
// 382.786 us; speedup vs baseline: 1.3002x; 1.3002x over previous
//
#include <hip/hip_runtime.h>
#include <math.h>

#define B_ 8
#define N_ 1024
#define C_ 768
#define H_ 8
#define D_ 96
#define SCALE_F 0.1020620726159657f /* 96^-0.5 */

typedef unsigned short u16;
typedef __bf16 bf16x8 __attribute__((ext_vector_type(8)));
typedef float f32x4 __attribute__((ext_vector_type(4)));

#define MFMA(a, b, c) __builtin_amdgcn_mfma_f32_16x16x32_bf16(a, b, c, 0, 0, 0)

__device__ inline void split1(float x, u16& h, u16& l) {
    __bf16 hb = (__bf16)x;
    float hf = (float)hb;
    __bf16 lb = (__bf16)(x - hf);
    h = __builtin_bit_cast(u16, hb);
    l = __builtin_bit_cast(u16, lb);
}

__device__ inline void split1b(float x, __bf16& h, __bf16& l) {
    h = (__bf16)x;
    l = (__bf16)(x - (float)h);
}

__device__ inline void split4(float4 x, ushort4& h, ushort4& l) {
    split1(x.x, h.x, l.x);
    split1(x.y, h.y, l.y);
    split1(x.z, h.z, l.z);
    split1(x.w, h.w, l.w);
}

// ---------------------------------------------------------------------------
// Kernel 1: conv3x3 (SAME) on 8192 images of 3x16x16.
// q,k written directly as bf16 hi/lo splits; v written f32 (transposed later).
// ---------------------------------------------------------------------------
__global__ __launch_bounds__(256) void conv_qkv(
    const float* __restrict__ x,
    const float* __restrict__ qw, const float* __restrict__ qb,
    const float* __restrict__ kw, const float* __restrict__ kb,
    const float* __restrict__ vw, const float* __restrict__ vb,
    u16* __restrict__ qh, u16* __restrict__ ql,
    u16* __restrict__ kh, u16* __restrict__ kl,
    float* __restrict__ v)
{
    __shared__ float simg[768];
    __shared__ float sw[243];
    __shared__ float sb[9];
    const int img = blockIdx.x;
    const int b = img >> 10;
    const int tid = threadIdx.x;

    for (int i = tid; i < 768; i += 256) simg[i] = x[(size_t)img * 768 + i];
    if (tid < 243) {
        int g = tid / 81, i = tid % 81;
        const float* w = (g == 0) ? qw : (g == 1) ? kw : vw;
        sw[tid] = w[i];
    }
    if (tid < 9) {
        int g = tid / 3, i = tid % 3;
        const float* bb = (g == 0) ? qb : (g == 1) ? kb : vb;
        sb[tid] = bb[i];
    }
    __syncthreads();

    const int n = img & 1023;
    for (int e = tid; e < 2304; e += 256) {
        int g = e / 768, c = e % 768;
        int oc = c >> 8, rem = c & 255, y = rem >> 4, xx = rem & 15;
        float acc = sb[g * 3 + oc];
        const float* wg = &sw[g * 81 + oc * 27];
        #pragma unroll
        for (int ic = 0; ic < 3; ++ic)
            #pragma unroll
            for (int ky = 0; ky < 3; ++ky) {
                int yy = y + ky - 1;
                if (yy < 0 || yy > 15) continue;
                #pragma unroll
                for (int kx = 0; kx < 3; ++kx) {
                    int xp = xx + kx - 1;
                    if (xp < 0 || xp > 15) continue;
                    acc += wg[ic * 9 + ky * 3 + kx] * simg[ic * 256 + yy * 16 + xp];
                }
            }
        int hh = c / 96, d = c % 96;
        size_t o = ((size_t)(b * 8 + hh) * 1024 + n) * 96 + d;
        if (g == 2) {
            v[o] = acc;
        } else {
            u16 hi, lo;
            split1(acc, hi, lo);
            if (g == 0) { qh[o] = hi; ql[o] = lo; }
            else        { kh[o] = hi; kl[o] = lo; }
        }
    }
}

// ---------------------------------------------------------------------------
// Kernel 2: transpose+split V: (b,h,n,d) f32 -> vt_h/vt_l (b,h,d,n) bf16
// ---------------------------------------------------------------------------
__global__ __launch_bounds__(256) void vt_split(
    const float* __restrict__ v, u16* __restrict__ vt_h, u16* __restrict__ vt_l)
{
    __shared__ float t32[32][36];
    const int bh = blockIdx.z, n0 = blockIdx.x * 32, d0 = blockIdx.y * 32;
    const int tid = threadIdx.x;
    {
        int nn = tid >> 3, c4 = (tid & 7) * 4;
        float4 x = *(const float4*)&v[((size_t)bh * 1024 + n0 + nn) * 96 + d0 + c4];
        t32[nn][c4] = x.x; t32[nn][c4 + 1] = x.y;
        t32[nn][c4 + 2] = x.z; t32[nn][c4 + 3] = x.w;
    }
    __syncthreads();
    {
        int d = tid >> 3, n4 = (tid & 7) * 4;
        float4 y = make_float4(t32[n4][d], t32[n4 + 1][d], t32[n4 + 2][d], t32[n4 + 3][d]);
        ushort4 h, l;
        split4(y, h, l);
        size_t o = ((size_t)bh * 96 + d0 + d) * 1024 + n0 + n4;
        *(ushort4*)&vt_h[o] = h;
        *(ushort4*)&vt_l[o] = l;
    }
}

// ---------------------------------------------------------------------------
// Kernel 3: split pw f32 -> pw_h/pw_l bf16
// ---------------------------------------------------------------------------
__global__ __launch_bounds__(256) void pw_split(
    const float* __restrict__ pw, u16* __restrict__ pwh, u16* __restrict__ pwl)
{
    int i = blockIdx.x * 256 + threadIdx.x;
    float4 x = *(const float4*)&pw[(size_t)i * 4];
    ushort4 h, l;
    split4(x, h, l);
    *(ushort4*)&pwh[(size_t)i * 4] = h;
    *(ushort4*)&pwl[(size_t)i * 4] = l;
}

// ---------------------------------------------------------------------------
// Kernel 4: fused stats + QK + softmax + head-mix + BN + attn-write + PV.
// grid 256 (flat), 512 thr (8 waves, wave = head = out-head).
// b = bid & 7  -> batch pinned to XCD (8 XCDs): per-XCD L2 holds ONE batch's
// K/V; the 32 CUs of an XCD share each m-tile.
// ---------------------------------------------------------------------------
__global__ __launch_bounds__(512) void fused_attn(
    const u16* __restrict__ qh, const u16* __restrict__ ql,
    const u16* __restrict__ kh, const u16* __restrict__ kl,
    const u16* __restrict__ vth, const u16* __restrict__ vtl,
    const float* __restrict__ rw, const float* __restrict__ rb,
    const float* __restrict__ bn_g, const float* __restrict__ bn_b,
    const float* __restrict__ bn_m, const float* __restrict__ bn_v,
    float* __restrict__ attn, u16* __restrict__ o1h, u16* __restrict__ o1l)
{
    __shared__ float p_lds[2][8][32][36];
    __shared__ float s_w2[8][8];
    __shared__ float s_b2[8];

    const int bid = blockIdx.x;
    const int b = bid & 7;
    const int n0 = (bid >> 3) * 32;
    const int tid = threadIdx.x, wid = tid >> 6, lane = tid & 63;
    const int l16 = lane & 15, kg = lane >> 4;
    const int h = wid;
    const size_t bh = (size_t)(b * 8 + h);

    if (tid < 64) {
        int o = tid >> 3, hh = tid & 7;
        float inv = bn_g[o] * rsqrtf(bn_v[o] + 1e-5f);
        s_w2[o][hh] = rw[o * 8 + hh] * inv;
        if (hh == 0) s_b2[o] = (rb[o] - bn_m[o]) * inv + bn_b[o];
    }

    // resident Q fragments (this wave's head, rows n0..n0+31)
    bf16x8 qhf[2][3], qlf[2][3];
    #pragma unroll
    for (int nf = 0; nf < 2; ++nf)
        #pragma unroll
        for (int ks = 0; ks < 3; ++ks) {
            size_t off = (bh * 1024 + n0 + nf * 16 + l16) * 96 + ks * 32 + kg * 8;
            qhf[nf][ks] = *(const bf16x8*)&qh[off];
            qlf[nf][ks] = *(const bf16x8*)&ql[off];
        }

    // ---- Phase 1: stats (online max / sum), no barriers ----
    float mx[2][4], ls[2][4];
    #pragma unroll
    for (int nf = 0; nf < 2; ++nf)
        #pragma unroll
        for (int r = 0; r < 4; ++r) { mx[nf][r] = -INFINITY; ls[nf][r] = 0.f; }

    #pragma unroll 1
    for (int mt = 0; mt < 16; ++mt) {
        const int m0 = mt * 64;
        f32x4 sacc[2][4];
        #pragma unroll
        for (int nf = 0; nf < 2; ++nf)
            #pragma unroll
            for (int mf = 0; mf < 4; ++mf) sacc[nf][mf] = (f32x4){0.f, 0.f, 0.f, 0.f};

        #pragma unroll
        for (int ks = 0; ks < 3; ++ks) {
            bf16x8 kbh[4], kbl[4];
            #pragma unroll
            for (int mf = 0; mf < 4; ++mf) {
                size_t off = (bh * 1024 + m0 + mf * 16 + l16) * 96 + ks * 32 + kg * 8;
                kbh[mf] = *(const bf16x8*)&kh[off];
                kbl[mf] = *(const bf16x8*)&kl[off];
            }
            #pragma unroll
            for (int nf = 0; nf < 2; ++nf)
                #pragma unroll
                for (int mf = 0; mf < 4; ++mf) {
                    sacc[nf][mf] = MFMA(qhf[nf][ks], kbh[mf], sacc[nf][mf]);
                    sacc[nf][mf] = MFMA(qhf[nf][ks], kbl[mf], sacc[nf][mf]);
                    sacc[nf][mf] = MFMA(qlf[nf][ks], kbh[mf], sacc[nf][mf]);
                }
        }

        #pragma unroll
        for (int nf = 0; nf < 2; ++nf)
            #pragma unroll
            for (int r = 0; r < 4; ++r) {
                float s0 = sacc[nf][0][r] * SCALE_F;
                float s1 = sacc[nf][1][r] * SCALE_F;
                float s2 = sacc[nf][2][r] * SCALE_F;
                float s3 = sacc[nf][3][r] * SCALE_F;
                float vmax = fmaxf(fmaxf(s0, s1), fmaxf(s2, s3));
                #pragma unroll
                for (int off = 1; off < 16; off <<= 1) vmax = fmaxf(vmax, __shfl_xor(vmax, off));
                float mnew = fmaxf(mx[nf][r], vmax);
                float ssum = __expf(s0 - mnew) + __expf(s1 - mnew) +
                             __expf(s2 - mnew) + __expf(s3 - mnew);
                #pragma unroll
                for (int off = 1; off < 16; off <<= 1) ssum += __shfl_xor(ssum, off);
                ls[nf][r] = ls[nf][r] * __expf(mx[nf][r] - mnew) + ssum;
                mx[nf][r] = mnew;
            }
    }

    float rv[2][4];
    #pragma unroll
    for (int nf = 0; nf < 2; ++nf)
        #pragma unroll
        for (int r = 0; r < 4; ++r) rv[nf][r] = 1.0f / ls[nf][r];

    __syncthreads();   // s_w2/s_b2 ready; align waves before main loop

    float w2r[8];
    #pragma unroll
    for (int hh = 0; hh < 8; ++hh) w2r[hh] = s_w2[h][hh];
    const float b2h = s_b2[h];

    f32x4 pvacc[2][6];
    #pragma unroll
    for (int nf = 0; nf < 2; ++nf)
        #pragma unroll
        for (int df = 0; df < 6; ++df) pvacc[nf][df] = (f32x4){0.f, 0.f, 0.f, 0.f};

    // ---- Phase 2: main loop, 1 barrier per iter ----
    #pragma unroll 1
    for (int mt = 0; mt < 32; ++mt) {
        const int m0 = mt * 32;
        const int buf = mt & 1;

        // V loads issued early; consumed at end of iter (mix hides latency)
        bf16x8 vbh[6], vbl[6];
        #pragma unroll
        for (int df = 0; df < 6; ++df) {
            size_t off = (bh * 96 + df * 16 + l16) * 1024 + m0 + kg * 8;
            vbh[df] = *(const bf16x8*)&vth[off];
            vbl[df] = *(const bf16x8*)&vtl[off];
        }

        // QK (bit-identical per-(n,m) chains to Phase 1)
        f32x4 sacc[2][2];
        #pragma unroll
        for (int nf = 0; nf < 2; ++nf)
            #pragma unroll
            for (int mf = 0; mf < 2; ++mf) sacc[nf][mf] = (f32x4){0.f, 0.f, 0.f, 0.f};
        #pragma unroll
        for (int ks = 0; ks < 3; ++ks) {
            bf16x8 kbh[2], kbl[2];
            #pragma unroll
            for (int mf = 0; mf < 2; ++mf) {
                size_t off = (bh * 1024 + m0 + mf * 16 + l16) * 96 + ks * 32 + kg * 8;
                kbh[mf] = *(const bf16x8*)&kh[off];
                kbl[mf] = *(const bf16x8*)&kl[off];
            }
            #pragma unroll
            for (int nf = 0; nf < 2; ++nf)
                #pragma unroll
                for (int mf = 0; mf < 2; ++mf) {
                    sacc[nf][mf] = MFMA(qhf[nf][ks], kbh[mf], sacc[nf][mf]);
                    sacc[nf][mf] = MFMA(qhf[nf][ks], kbl[mf], sacc[nf][mf]);
                    sacc[nf][mf] = MFMA(qlf[nf][ks], kbh[mf], sacc[nf][mf]);
                }
        }

        // exp + normalized p -> p_lds[buf]
        #pragma unroll
        for (int nf = 0; nf < 2; ++nf)
            #pragma unroll
            for (int mf = 0; mf < 2; ++mf)
                #pragma unroll
                for (int r = 0; r < 4; ++r) {
                    float pp = __expf(sacc[nf][mf][r] * SCALE_F - mx[nf][r]) * rv[nf][r];
                    p_lds[buf][h][nf * 16 + kg * 4 + r][mf * 16 + l16] = pp;
                }
        __syncthreads();

        // cross-head mix (A-fragment layout: row n = l16, k = kg*8+j)
        float mixf[2][8];
        #pragma unroll
        for (int nf = 0; nf < 2; ++nf)
            #pragma unroll
            for (int j = 0; j < 8; ++j) mixf[nf][j] = b2h;
        #pragma unroll
        for (int hh = 0; hh < 8; ++hh) {
            float w = w2r[hh];
            #pragma unroll
            for (int nf = 0; nf < 2; ++nf) {
                const float* pp = &p_lds[buf][hh][nf * 16 + l16][kg * 8];
                float4 a0 = *(const float4*)pp;
                float4 a1 = *(const float4*)(pp + 4);
                mixf[nf][0] += w * a0.x; mixf[nf][1] += w * a0.y;
                mixf[nf][2] += w * a0.z; mixf[nf][3] += w * a0.w;
                mixf[nf][4] += w * a1.x; mixf[nf][5] += w * a1.y;
                mixf[nf][6] += w * a1.z; mixf[nf][7] += w * a1.w;
            }
        }

        // nontemporal attn write (kg-quads give contiguous 128B per row)
        #pragma unroll
        for (int nf = 0; nf < 2; ++nf) {
            float* gp = &attn[(bh * 1024 + n0 + nf * 16 + l16) * 1024 + m0 + kg * 8];
            f32x4 v0 = {mixf[nf][0], mixf[nf][1], mixf[nf][2], mixf[nf][3]};
            f32x4 v1 = {mixf[nf][4], mixf[nf][5], mixf[nf][6], mixf[nf][7]};
            __builtin_nontemporal_store(v0, (f32x4*)gp);
            __builtin_nontemporal_store(v1, (f32x4*)(gp + 4));
        }

        // split mixed to bf16 A-frags + PV accumulate
        bf16x8 mah[2], mal[2];
        #pragma unroll
        for (int nf = 0; nf < 2; ++nf)
            #pragma unroll
            for (int j = 0; j < 8; ++j) {
                __bf16 hb, lb;
                split1b(mixf[nf][j], hb, lb);
                mah[nf][j] = hb;
                mal[nf][j] = lb;
            }
        #pragma unroll
        for (int df = 0; df < 6; ++df)
            #pragma unroll
            for (int nf = 0; nf < 2; ++nf) {
                pvacc[nf][df] = MFMA(mah[nf], vbh[df], pvacc[nf][df]);
                pvacc[nf][df] = MFMA(mah[nf], vbl[df], pvacc[nf][df]);
                pvacc[nf][df] = MFMA(mal[nf], vbh[df], pvacc[nf][df]);
            }
    }

    // ---- epilogue: out1 (b, n, h*96+d) split bf16 h/l ----
    #pragma unroll
    for (int nf = 0; nf < 2; ++nf)
        #pragma unroll
        for (int df = 0; df < 6; ++df)
            #pragma unroll
            for (int r = 0; r < 4; ++r) {
                int row = n0 + nf * 16 + kg * 4 + r;
                int col = h * 96 + df * 16 + l16;
                u16 hh2, ll2;
                split1(pvacc[nf][df][r], hh2, ll2);
                size_t o = ((size_t)b * 1024 + row) * 768 + col;
                o1h[o] = hh2;
                o1l[o] = ll2;
            }
}

// ---------------------------------------------------------------------------
// Kernel 5: proj via MFMA. out[t][o] = out1[t][:] . pw[o][:] + pb[o]
// ---------------------------------------------------------------------------
__global__ __launch_bounds__(256) void proj_mfma(
    const u16* __restrict__ o1h, const u16* __restrict__ o1l,
    const u16* __restrict__ pwh, const u16* __restrict__ pwl,
    const float* __restrict__ pb, float* __restrict__ out)
{
    __shared__ __align__(16) u16 Ahs[5120], Als[5120];  // [128][40]
    __shared__ __align__(16) u16 Bhs[2560], Bls[2560];  // [64][40]
    const int t0 = blockIdx.y * 128, o0 = blockIdx.x * 64;
    const int tid = threadIdx.x;
    const int wid = tid >> 6, lane = tid & 63;
    const int l16 = lane & 15, kg = lane >> 4;
    const int wr = wid >> 1, wc = wid & 1;

    f32x4 acc[4][2];
    #pragma unroll
    for (int i = 0; i < 4; ++i)
        #pragma unroll
        for (int j = 0; j < 2; ++j) acc[i][j] = (f32x4){0.f, 0.f, 0.f, 0.f};

    for (int s = 0; s < 24; ++s) {
        const int kc = s * 32;
        if (s) __syncthreads();
        #pragma unroll
        for (int i = 0; i < 4; ++i) {
            int idx = tid + i * 256;
            int r = idx >> 3, c4 = idx & 7;
            *(ushort4*)&Ahs[r * 40 + c4 * 4] = *(const ushort4*)&o1h[(size_t)(t0 + r) * 768 + kc + c4 * 4];
            *(ushort4*)&Als[r * 40 + c4 * 4] = *(const ushort4*)&o1l[(size_t)(t0 + r) * 768 + kc + c4 * 4];
        }
        #pragma unroll
        for (int i = 0; i < 2; ++i) {
            int idx = tid + i * 256;
            int r = idx >> 3, c4 = idx & 7;
            *(ushort4*)&Bhs[r * 40 + c4 * 4] = *(const ushort4*)&pwh[(size_t)(o0 + r) * 768 + kc + c4 * 4];
            *(ushort4*)&Bls[r * 40 + c4 * 4] = *(const ushort4*)&pwl[(size_t)(o0 + r) * 768 + kc + c4 * 4];
        }
        __syncthreads();

        bf16x8 ah[4], al[4], bh8[2], bl8[2];
        #pragma unroll
        for (int f = 0; f < 4; ++f) {
            int ra = (wr * 64 + f * 16 + l16) * 40 + kg * 8;
            ah[f] = *(const bf16x8*)&Ahs[ra];
            al[f] = *(const bf16x8*)&Als[ra];
        }
        #pragma unroll
        for (int j = 0; j < 2; ++j) {
            int rb = (wc * 32 + j * 16 + l16) * 40 + kg * 8;
            bh8[j] = *(const bf16x8*)&Bhs[rb];
            bl8[j] = *(const bf16x8*)&Bls[rb];
        }
        #pragma unroll
        for (int i = 0; i < 4; ++i)
            #pragma unroll
            for (int j = 0; j < 2; ++j) {
                acc[i][j] = MFMA(ah[i], bh8[j], acc[i][j]);
                acc[i][j] = MFMA(ah[i], bl8[j], acc[i][j]);
                acc[i][j] = MFMA(al[i], bh8[j], acc[i][j]);
            }
    }

    #pragma unroll
    for (int i = 0; i < 4; ++i) {
        int rr = t0 + wr * 64 + i * 16 + kg * 4;
        #pragma unroll
        for (int j = 0; j < 2; ++j) {
            int cc = o0 + wc * 32 + j * 16 + l16;
            float bias = pb[cc];
            #pragma unroll
            for (int r = 0; r < 4; ++r)
                __builtin_nontemporal_store(acc[i][j][r] + bias,
                                            &out[(size_t)(rr + r) * 768 + cc]);
        }
    }
}

// ---------------------------------------------------------------------------
extern "C" void kernel_launch(void* const* d_in, const int* in_sizes, int n_in,
                              void* d_out, int out_size, void* d_ws, size_t ws_size,
                              hipStream_t stream)
{
    const float* x    = (const float*)d_in[0];
    const float* qw   = (const float*)d_in[1];
    const float* qb   = (const float*)d_in[2];
    const float* kw   = (const float*)d_in[3];
    const float* kb   = (const float*)d_in[4];
    const float* vw   = (const float*)d_in[5];
    const float* vb   = (const float*)d_in[6];
    const float* rw   = (const float*)d_in[7];
    const float* rb   = (const float*)d_in[8];
    const float* bn_g = (const float*)d_in[9];
    const float* bn_b = (const float*)d_in[10];
    const float* bn_m = (const float*)d_in[11];
    const float* bn_v = (const float*)d_in[12];
    const float* pw   = (const float*)d_in[13];
    const float* pb   = (const float*)d_in[14];

    float* out_p  = (float*)d_out;                  // (B, N, C)
    float* attn_p = out_p + (size_t)B_ * N_ * C_;   // (B, H, N, N)

    float* ws = (float*)d_ws;
    const size_t qkv = (size_t)B_ * H_ * N_ * D_;   // 6,291,456

    float* vf  = ws;                                // v f32 (1 qkv floats)
    u16* qhp = (u16*)(ws + qkv);                    // 4 u16 bufs = 2 qkv floats
    u16* qlp = qhp + qkv;
    u16* khp = qlp + qkv;
    u16* klp = khp + qkv;
    u16* vth = (u16*)(ws + 3 * qkv);                // 1 qkv floats
    u16* vtl = vth + qkv;
    u16* o1h = (u16*)(ws + 4 * qkv);                // 1 qkv floats
    u16* o1l = o1h + qkv;
    u16* pwh = (u16*)(ws + 5 * qkv);                // 589824 u16 x2
    u16* pwl = pwh + (size_t)C_ * C_;

    conv_qkv<<<B_ * N_, 256, 0, stream>>>(x, qw, qb, kw, kb, vw, vb,
                                          qhp, qlp, khp, klp, vf);
    vt_split<<<dim3(32, 3, 64), 256, 0, stream>>>(vf, vth, vtl);
    pw_split<<<576, 256, 0, stream>>>(pw, pwh, pwl);
    fused_attn<<<256, 512, 0, stream>>>(qhp, qlp, khp, klp, vth, vtl,
                                        rw, rb, bn_g, bn_b, bn_m, bn_v,
                                        attn_p, o1h, o1l);
    proj_mfma<<<dim3(12, 64), 256, 0, stream>>>(o1h, o1l, pwh, pwl, pb, out_p);
}